// Round 5
// baseline (541.144 us; speedup 1.0000x reference)
//
#include <hip/hip_runtime.h>
#include <hip/hip_bf16.h>

#define B_ 8
#define N_ 4096
#define E_ 131072
#define D_ 64
#define H_ 128

#define EDGE_BLOCKS 256
#define ETILE 256
#define TILES_TOTAL ((B_ * E_) / ETILE)               // 4096 tiles of 256 edges
#define TILES_PER_BLOCK (TILES_TOTAL / EDGE_BLOCKS)   // 16

typedef unsigned int u32;
typedef short bf16x8 __attribute__((ext_vector_type(8)));
typedef float f32x4 __attribute__((ext_vector_type(4)));

__device__ __forceinline__ unsigned short f2bf(float f) {
  u32 x = __float_as_uint(f);
  x += 0x7fffu + ((x >> 16) & 1u);   // RNE
  return (unsigned short)(x >> 16);
}
__device__ __forceinline__ float bf2f(unsigned short v) {
  return __uint_as_float(((u32)v) << 16);
}
__device__ __forceinline__ u32 cvt_pk_bf16(float lo, float hi) {
  u32 r;
  asm("v_cvt_pk_bf16_f32 %0, %1, %2" : "=v"(r) : "v"(lo), "v"(hi));
  return r;
}
__device__ __forceinline__ float silu_f(float x) { return x / (1.0f + __expf(-x)); }

// XOR-swizzled u16 index into a [rows][128] bf16 LDS tile (row stride 256 B).
__device__ __forceinline__ int swz(int row, int col) {
  return row * 128 + (col ^ ((row & 7) << 3));
}

#define MFMA(a, b, c) __builtin_amdgcn_mfma_f32_16x16x32_bf16(a, b, c, 0, 0, 0)

// ---------------- prep kernels ----------------
__global__ void nf2bf_k(const float* __restrict__ nf, unsigned short* __restrict__ nf16) {
  const int i = blockIdx.x * 256 + threadIdx.x;
  float4 v = ((const float4*)nf)[i];
  u32 p0 = cvt_pk_bf16(v.x, v.y);
  u32 p1 = cvt_pk_bf16(v.z, v.w);
  ((uint2*)nf16)[i] = make_uint2(p0, p1);
}

__global__ void hist_k(const int* __restrict__ ei, int* __restrict__ hist) {
  const int e = blockIdx.x * 256 + threadIdx.x;
  atomicAdd(&hist[ei[E_ + e]], 1);
}

__global__ __launch_bounds__(1024) void scan4096(int* __restrict__ h) {
  __shared__ int wsums[16];
  const int tid = threadIdx.x;
  const int lane = tid & 63, wv = tid >> 6;
  int4 v = ((int4*)h)[tid];
  const int s = v.x + v.y + v.z + v.w;
  int incl = s;
#pragma unroll
  for (int off = 1; off < 64; off <<= 1) {
    int u = __shfl_up(incl, off);
    if (lane >= off) incl += u;
  }
  if (lane == 63) wsums[wv] = incl;
  __syncthreads();
  if (wv == 0) {
    int ws = (lane < 16) ? wsums[lane] : 0;
#pragma unroll
    for (int off = 1; off < 16; off <<= 1) {
      int u = __shfl_up(ws, off);
      if (lane >= off) ws += u;
    }
    if (lane < 16) wsums[lane] = ws;
  }
  __syncthreads();
  int base = (wv ? wsums[wv - 1] : 0) + (incl - s);
  int4 o;
  o.x = base; o.y = base + v.x; o.z = o.y + v.y; o.w = o.z + v.z;
  ((int4*)h)[tid] = o;
}

__global__ void scatter_k(const int* __restrict__ ei, int* __restrict__ offs,
                          int* __restrict__ src_s, int* __restrict__ dst_s) {
  const int e = blockIdx.x * 256 + threadIdx.x;
  const int d = ei[E_ + e];
  const int p = atomicAdd(&offs[d], 1);
  src_s[p] = ei[e];
  dst_s[p] = d;
}

// ---------------- edge kernel: 256-edge tiles, reg-pipelined gather ----------------
__global__ __launch_bounds__(1024, 4) void egnn_edge_mfma(
    const unsigned short* __restrict__ nf16, const float* __restrict__ coords,
    const int* __restrict__ src_s, const int* __restrict__ dst_s,
    const float* __restrict__ Wm1, const float* __restrict__ bm1,
    const float* __restrict__ Wm2, const float* __restrict__ bm2,
    const float* __restrict__ Wc1, const float* __restrict__ bc1,
    const float* __restrict__ Wc2, const float* __restrict__ bc2,
    float* __restrict__ agg, float* __restrict__ cdelta)
{
  __shared__ unsigned short sW1[128 * 128];       // 32 KB
  __shared__ unsigned short sW2[128 * 128];       // 32 KB
  __shared__ unsigned short buf[ETILE * 128];     // 64 KB: msg -> h -> m
  __shared__ float4 sgeo[2][ETILE];               // 8 KB
  __shared__ int sdst[2][ETILE];                  // 2 KB
  __shared__ float swpart[4][ETILE];              // 4 KB

  const int tid = threadIdx.x;
  for (int i = tid; i < 128 * 128; i += 1024) {
    const int k = i >> 7, n = i & 127;
    const int d = swz(n, k);
    sW1[d] = f2bf(Wm1[i]);
    sW2[d] = f2bf(Wm2[i]);
  }

  const int lane = tid & 63;
  const int w = tid >> 6;
  const int l15 = lane & 15;
  const int l4 = lane >> 4;
  const int k0l = l4 * 8;
  const int rowbase = (w >> 2) * 64;   // 4 row-groups of 64 rows
  const int colbase = (w & 3) * 32;    // 4 col-groups of 32 cols
  const int n0 = colbase + l15;
  const int n1 = n0 + 16;

  // per-thread epilogue constants
  const float bb1_0 = bm1[n0], bb1_1 = bm1[n1];
  const float bb2_0 = bm2[n0], bb2_1 = bm2[n1];
  const float bb3_0 = bc1[n0], bb3_1 = bc1[n1];
  const float wc2_0 = Wc2[n0], wc2_1 = Wc2[n1];
  const float wr_0 = Wm1[128 * 128 + n0], wr_1 = Wm1[128 * 128 + n1];
  const float bc2v = bc2[0];

  // Wc1 B-fragments in registers (tile-invariant): w3f[cb][ks]
  bf16x8 w3f[2][4];
#pragma unroll
  for (int cb = 0; cb < 2; ++cb) {
    const int n = colbase + cb * 16 + l15;
#pragma unroll
    for (int ks = 0; ks < 4; ++ks) {
      bf16x8 v;
#pragma unroll
      for (int j = 0; j < 8; ++j)
        v[j] = (short)f2bf(Wc1[(ks * 32 + k0l + j) * 128 + n]);
      w3f[cb][ks] = v;
    }
  }

  // XCD swizzle: one batch per XCD
  const int myblk = (blockIdx.x & 7) * (EDGE_BLOCKS / 8) + (blockIdx.x >> 3);
  const int b = myblk >> 5;                     // 32 blocks per batch
  const int gbase = (myblk & 31) * TILES_PER_BLOCK;

  // gather roles
  const int m_p = tid >> 2;          // row 0..255
  const int q_p = tid & 3;           // granule quad 0..3 (q<2: src, q>=2: dst)

  // ---- prologue: tile-0 geometry + register prefetch ----
  {
    const int ebase0 = gbase * ETILE;
    if (tid < ETILE) {
      const int e = ebase0 + tid;
      const int s = src_s[e];
      const int d = dst_s[e];
      sdst[0][tid] = d;
      const float* cs = coords + (size_t)(b * N_ + s) * 3;
      const float* cd = coords + (size_t)(b * N_ + d) * 3;
      const float d0 = cd[0] - cs[0], d1 = cd[1] - cs[1], d2 = cd[2] - cs[2];
      const float dist = sqrtf(fmaf(d0, d0, fmaf(d1, d1, d2 * d2)));
      sgeo[0][tid] = make_float4(d0, d1, d2, dist);
    }
  }
  uint4 pf[4];
  {
    const int e = gbase * ETILE + m_p;
    const int node = (q_p < 2) ? src_s[e] : dst_s[e];
    const unsigned short* np = nf16 + (size_t)(b * N_ + node) * 64 + (q_p & 1) * 32;
#pragma unroll
    for (int j = 0; j < 4; ++j) pf[j] = *(const uint4*)(np + j * 8);
  }

  f32x4 acc[4][2];

  for (int t = 0; t < TILES_PER_BLOCK; ++t) {
    const int p = t & 1;

    // ---- commit prefetched msg rows to LDS (swizzled) ----
#pragma unroll
    for (int j = 0; j < 4; ++j)
      *(uint4*)&buf[swz(m_p, (q_p * 4 + j) * 8)] = pf[j];
    __syncthreads();   // B1: msg visible; prior tile fully retired

    // ---- issue next tile's prefetch (regs) + geometry (parity p^1) ----
    {
      const int tt = (t + 1 < TILES_PER_BLOCK) ? t + 1 : t;
      const int ebase2 = (gbase + tt) * ETILE;
      const int e = ebase2 + m_p;
      const int node = (q_p < 2) ? src_s[e] : dst_s[e];
      const unsigned short* np = nf16 + (size_t)(b * N_ + node) * 64 + (q_p & 1) * 32;
#pragma unroll
      for (int j = 0; j < 4; ++j) pf[j] = *(const uint4*)(np + j * 8);
      if (tid < ETILE) {
        const int e2 = ebase2 + tid;
        const int s = src_s[e2];
        const int d = dst_s[e2];
        sdst[p ^ 1][tid] = d;
        const float* cs = coords + (size_t)(b * N_ + s) * 3;
        const float* cd = coords + (size_t)(b * N_ + d) * 3;
        const float d0 = cd[0] - cs[0], d1 = cd[1] - cs[1], d2 = cd[2] - cs[2];
        const float dist = sqrtf(fmaf(d0, d0, fmaf(d1, d1, d2 * d2)));
        sgeo[p ^ 1][tid] = make_float4(d0, d1, d2, dist);
      }
    }

    // ---- L1: h = silu(msg @ Wm1 + bm1 + dist * Wm1[128,:]) ----
    {
      f32x4 z = {0.f, 0.f, 0.f, 0.f};
#pragma unroll
      for (int i = 0; i < 4; ++i) { acc[i][0] = z; acc[i][1] = z; }
    }
#pragma unroll
    for (int ks = 0; ks < 4; ++ks) {
      const int k = ks * 32 + k0l;
      bf16x8 b0 = *(const bf16x8*)&sW1[swz(colbase + l15, k)];
      bf16x8 b1 = *(const bf16x8*)&sW1[swz(colbase + 16 + l15, k)];
#pragma unroll
      for (int i = 0; i < 4; ++i) {
        bf16x8 a = *(const bf16x8*)&buf[swz(rowbase + 16 * i + l15, k)];
        acc[i][0] = MFMA(a, b0, acc[i][0]);
        acc[i][1] = MFMA(a, b1, acc[i][1]);
      }
    }
    float hv0[4][4], hv1[4][4];
#pragma unroll
    for (int i = 0; i < 4; ++i)
#pragma unroll
      for (int r = 0; r < 4; ++r) {
        const int m = rowbase + 16 * i + l4 * 4 + r;
        const float dist = sgeo[p][m].w;
        hv0[i][r] = silu_f(acc[i][0][r] + bb1_0 + dist * wr_0);
        hv1[i][r] = silu_f(acc[i][1][r] + bb1_1 + dist * wr_1);
      }
    __syncthreads();   // B2: msg reads done
#pragma unroll
    for (int i = 0; i < 4; ++i)
#pragma unroll
      for (int r = 0; r < 4; ++r) {
        const int m = rowbase + 16 * i + l4 * 4 + r;
        const u32 pk = cvt_pk_bf16(hv0[i][r], hv1[i][r]);
        buf[swz(m, n0)] = (unsigned short)pk;
        buf[swz(m, n1)] = (unsigned short)(pk >> 16);
      }
    __syncthreads();   // B3: h visible

    // ---- L2: m = h @ Wm2 + bm2 ----
    {
      f32x4 z = {0.f, 0.f, 0.f, 0.f};
#pragma unroll
      for (int i = 0; i < 4; ++i) { acc[i][0] = z; acc[i][1] = z; }
    }
#pragma unroll
    for (int ks = 0; ks < 4; ++ks) {
      const int k = ks * 32 + k0l;
      bf16x8 b0 = *(const bf16x8*)&sW2[swz(colbase + l15, k)];
      bf16x8 b1 = *(const bf16x8*)&sW2[swz(colbase + 16 + l15, k)];
#pragma unroll
      for (int i = 0; i < 4; ++i) {
        bf16x8 a = *(const bf16x8*)&buf[swz(rowbase + 16 * i + l15, k)];
        acc[i][0] = MFMA(a, b0, acc[i][0]);
        acc[i][1] = MFMA(a, b1, acc[i][1]);
      }
    }
    float mv0[4][4], mv1[4][4];
#pragma unroll
    for (int i = 0; i < 4; ++i)
#pragma unroll
      for (int r = 0; r < 4; ++r) {
        mv0[i][r] = acc[i][0][r] + bb2_0;
        mv1[i][r] = acc[i][1][r] + bb2_1;
      }
    __syncthreads();   // B4: h reads done
#pragma unroll
    for (int i = 0; i < 4; ++i)
#pragma unroll
      for (int r = 0; r < 4; ++r) {
        const int m = rowbase + 16 * i + l4 * 4 + r;
        const u32 pk = cvt_pk_bf16(mv0[i][r], mv1[i][r]);
        buf[swz(m, n0)] = (unsigned short)pk;
        buf[swz(m, n1)] = (unsigned short)(pk >> 16);
      }
    __syncthreads();   // B5: m visible

    // ---- L3: c = silu(m @ Wc1 + bc1); partial w = c . Wc2 ----
    {
      f32x4 z = {0.f, 0.f, 0.f, 0.f};
#pragma unroll
      for (int i = 0; i < 4; ++i) { acc[i][0] = z; acc[i][1] = z; }
    }
#pragma unroll
    for (int ks = 0; ks < 4; ++ks) {
      const int k = ks * 32 + k0l;
#pragma unroll
      for (int i = 0; i < 4; ++i) {
        bf16x8 a = *(const bf16x8*)&buf[swz(rowbase + 16 * i + l15, k)];
        acc[i][0] = MFMA(a, w3f[0][ks], acc[i][0]);
        acc[i][1] = MFMA(a, w3f[1][ks], acc[i][1]);
      }
    }
#pragma unroll
    for (int i = 0; i < 4; ++i)
#pragma unroll
      for (int r = 0; r < 4; ++r) {
        float pw = silu_f(acc[i][0][r] + bb3_0) * wc2_0 +
                   silu_f(acc[i][1][r] + bb3_1) * wc2_1;
        pw += __shfl_xor(pw, 1);
        pw += __shfl_xor(pw, 2);
        pw += __shfl_xor(pw, 4);
        pw += __shfl_xor(pw, 8);
        if (l15 == 0) swpart[w & 3][rowbase + 16 * i + l4 * 4 + r] = pw;
      }

    // ---- agg run-reduction: thread (col=tid&127, group=tid>>7) scans 32 rows ----
    {
      const int c = tid & 127;
      int r = (tid >> 7) * 32;
      int cur = sdst[p][r];
      float accs = 0.f;
#pragma unroll 4
      for (int k = 0; k < 32; ++k, ++r) {
        const int d2 = sdst[p][r];
        if (d2 != cur) {   // uniform per wave
          unsafeAtomicAdd(agg + ((size_t)(b * N_ + cur)) * H_ + c, accs);
          accs = 0.f;
          cur = d2;
        }
        accs += bf2f(buf[swz(r, c)]);
      }
      unsafeAtomicAdd(agg + ((size_t)(b * N_ + cur)) * H_ + c, accs);
    }
    __syncthreads();   // B6: buf reads done, swpart ready

    // ---- coord scatter: segmented scan over 256 sorted rows (waves 0-3) ----
    if (tid < ETILE) {
      float wc = bc2v;
#pragma unroll
      for (int cg = 0; cg < 4; ++cg) wc += swpart[cg][tid];
      const float4 g = sgeo[p][tid];
      const float inv = 1.0f / (g.w + 1e-8f);
      float vx = wc * g.x * inv, vy = wc * g.y * inv, vz = wc * g.z * inv;
      const int myd = sdst[p][tid];
      int flg = (lane == 0) ? 1 : (sdst[p][tid - 1] != myd);
#pragma unroll
      for (int off = 1; off < 64; off <<= 1) {
        float ux = __shfl_up(vx, off);
        float uy = __shfl_up(vy, off);
        float uz = __shfl_up(vz, off);
        int uf = __shfl_up(flg, off);
        if (lane >= off) {
          if (!flg) { vx += ux; vy += uy; vz += uz; }
          flg |= uf;
        }
      }
      const bool tail = (lane == 63) || (sdst[p][tid + 1] != myd);
      if (tail) {
        float* bp = cdelta + ((size_t)(b * N_ + myd)) * 3;
        unsafeAtomicAdd(bp + 0, vx);
        unsafeAtomicAdd(bp + 1, vy);
        unsafeAtomicAdd(bp + 2, vz);
      }
    }
    // next loop-top buf writes are safe: all buf reads retired before B6
  }
}

// ---------------- node kernel (unchanged) ----------------
__device__ __forceinline__ float bfbits(u32 x) { return __uint_as_float(x); }

__global__ __launch_bounds__(512, 2) void egnn_node(
    const float* __restrict__ nf, const float* __restrict__ coords,
    const float* __restrict__ agg, const float* __restrict__ cdelta,
    const float* __restrict__ Wn1, const float* __restrict__ bn1,
    const float* __restrict__ Wn2, const float* __restrict__ bn2,
    float* __restrict__ out_nf, float* __restrict__ out_c)
{
  __shared__ unsigned short sWn1[192 * H_];
  __shared__ unsigned short sWn2[H_ * D_];
  __shared__ float sb[192];
  __shared__ float swork[8][328];

  const int tid = threadIdx.x;
  for (int i = tid; i < 192 * H_; i += 512) sWn1[i] = f2bf(Wn1[i]);
  for (int i = tid; i < H_ * D_; i += 512) sWn2[i] = f2bf(Wn2[i]);
  if (tid < 128) sb[tid] = bn1[tid];
  if (tid >= 128 && tid < 192) sb[tid] = bn2[tid - 128];
  __syncthreads();

  const int wave = tid >> 6;
  const int lane = tid & 63;
  float* W = swork[wave];

  const int total = B_ * N_;
  const int stride = gridDim.x * 8;

  for (int task = blockIdx.x * 8 + wave; task < total; task += stride) {
    const float* nfp = nf + (size_t)task * D_;
    const float* ap = agg + (size_t)task * H_;
    W[lane] = nfp[lane];
    W[64 + lane] = ap[lane];
    W[128 + lane] = ap[64 + lane];
    __syncthreads();

    {
      const unsigned short* wp = sWn1 + 2 * lane;
      float a0 = 0.f, a1 = 0.f, a2 = 0.f, a3 = 0.f;
#pragma unroll 8
      for (int k = 0; k < 192; k += 2) {
        float2 x = *(const float2*)&W[k];
        u32 p0 = *(const u32*)(wp + k * H_);
        u32 p1 = *(const u32*)(wp + (k + 1) * H_);
        a0 = fmaf(x.x, bfbits(p0 << 16), a0);
        a1 = fmaf(x.x, bfbits(p0 & 0xffff0000u), a1);
        a2 = fmaf(x.y, bfbits(p1 << 16), a2);
        a3 = fmaf(x.y, bfbits(p1 & 0xffff0000u), a3);
      }
      float h0 = silu_f(a0 + a2 + sb[2 * lane]);
      float h1 = silu_f(a1 + a3 + sb[2 * lane + 1]);
      ((float2*)(W + 192))[lane] = make_float2(h0, h1);
    }
    __syncthreads();

    {
      float a0 = 0.f, a1 = 0.f, a2 = 0.f, a3 = 0.f;
#pragma unroll 8
      for (int k = 0; k < 128; k += 4) {
        float2 xa = *(const float2*)&W[192 + k];
        float2 xb = *(const float2*)&W[192 + k + 2];
        a0 = fmaf(xa.x, bfbits(((u32)sWn2[(k + 0) * D_ + lane]) << 16), a0);
        a1 = fmaf(xa.y, bfbits(((u32)sWn2[(k + 1) * D_ + lane]) << 16), a1);
        a2 = fmaf(xb.x, bfbits(((u32)sWn2[(k + 2) * D_ + lane]) << 16), a2);
        a3 = fmaf(xb.y, bfbits(((u32)sWn2[(k + 3) * D_ + lane]) << 16), a3);
      }
      out_nf[(size_t)task * D_ + lane] =
          nfp[lane] + (a0 + a1 + a2 + a3) + sb[128 + lane];
      if (lane < 3) {
        out_c[(size_t)task * 3 + lane] =
            coords[(size_t)task * 3 + lane] + cdelta[(size_t)task * 3 + lane];
      }
    }
    __syncthreads();
  }
}

extern "C" void kernel_launch(void* const* d_in, const int* in_sizes, int n_in,
                              void* d_out, int out_size, void* d_ws, size_t ws_size,
                              hipStream_t stream) {
  const float* nf     = (const float*)d_in[0];
  const float* coords = (const float*)d_in[1];
  const int*   ei     = (const int*)d_in[2];
  const float* Wm1 = (const float*)d_in[3];
  const float* bm1 = (const float*)d_in[4];
  const float* Wm2 = (const float*)d_in[5];
  const float* bm2 = (const float*)d_in[6];
  const float* Wn1 = (const float*)d_in[7];
  const float* bn1 = (const float*)d_in[8];
  const float* Wn2 = (const float*)d_in[9];
  const float* bn2 = (const float*)d_in[10];
  const float* Wc1 = (const float*)d_in[11];
  const float* bc1 = (const float*)d_in[12];
  const float* Wc2 = (const float*)d_in[13];
  const float* bc2 = (const float*)d_in[14];

  // workspace (floats): agg | cdelta | hist(4096 i) | src_s | dst_s
  float* agg    = (float*)d_ws;
  float* cdelta = agg + (size_t)B_ * N_ * H_;
  int*   hist   = (int*)(cdelta + (size_t)B_ * N_ * 3);
  int*   src_s  = hist + 4096;
  int*   dst_s  = src_s + E_;

  float* out_nf = (float*)d_out;
  float* out_c  = out_nf + (size_t)B_ * N_ * D_;

  // nf16 scratch in d_out's head; node kernel fully overwrites d_out later.
  unsigned short* nf16 = (unsigned short*)d_out;

  const size_t zero_bytes =
      ((size_t)B_ * N_ * H_ + (size_t)B_ * N_ * 3 + 4096) * sizeof(float);
  hipMemsetAsync(d_ws, 0, zero_bytes, stream);

  nf2bf_k<<<(B_ * N_ * D_ / 4) / 256, 256, 0, stream>>>(nf, nf16);
  hist_k<<<E_ / 256, 256, 0, stream>>>(ei, hist);
  scan4096<<<1, 1024, 0, stream>>>(hist);
  scatter_k<<<E_ / 256, 256, 0, stream>>>(ei, hist, src_s, dst_s);

  egnn_edge_mfma<<<EDGE_BLOCKS, 1024, 0, stream>>>(
      nf16, coords, src_s, dst_s, Wm1, bm1, Wm2, bm2, Wc1, bc1, Wc2, bc2,
      agg, cdelta);
  egnn_node<<<512, 512, 0, stream>>>(nf, coords, agg, cdelta,
                                     Wn1, bn1, Wn2, bn2, out_nf, out_c);
}